// Round 5
// baseline (589.344 us; speedup 1.0000x reference)
//
#include <hip/hip_runtime.h>
#include <math.h>

#define N_NODES 50000
#define N_PAD   50048              // rows padded to multiple of 64
#define N_EDGES 1600000
#define DIM     128
#define RCUT    5.0f
#define NB_CONV 6250               // convert blocks in pre
#define NB_WPREP 8                 // wprep blocks in pre
#define NB_HIST 512                // histogram blocks in pre
#define CH_HIST (N_EDGES / NB_HIST)
#define NB_RE   512                // reorder blocks
#define CH_RE   (N_EDGES / NB_RE)
#define XPAD    136                // LDS X tile row stride in bf16 (272 B)
#define NTILE   (N_PAD / 16)       // 3128 16-node tiles per layer

typedef __attribute__((ext_vector_type(8))) __bf16 bf16x8;
typedef __attribute__((ext_vector_type(4))) float  f32x4;

// ---------------- bf16 helpers ----------------
__device__ __forceinline__ float bf_lo(unsigned int u) { return __uint_as_float(u << 16); }
__device__ __forceinline__ float bf_hi(unsigned int u) { return __uint_as_float(u & 0xffff0000u); }
__device__ __forceinline__ unsigned short f2bf(float x) {
    unsigned int u = __float_as_uint(x);
    u += 0x7fffu + ((u >> 16) & 1u);   // round-to-nearest-even
    return (unsigned short)(u >> 16);
}

// ---------------- pre: v->bf16 | W->frags | node histogram (global atomics) --
__global__ __launch_bounds__(256) void pre_kernel(
        const float* __restrict__ v, unsigned short* __restrict__ vb,
        const float* __restrict__ Aw, uint4* __restrict__ wfrag,
        const int* __restrict__ dst, int* __restrict__ hist) {
    int b = blockIdx.x;
    if (b < NB_CONV) {
        int i = b * 256 + threadIdx.x;           // exactly N_NODES*DIM/4
        float4 x = ((const float4*)v)[i];
        uint2 o;
        o.x = (unsigned)f2bf(x.x) | ((unsigned)f2bf(x.y) << 16);
        o.y = (unsigned)f2bf(x.z) | ((unsigned)f2bf(x.w) << 16);
        ((uint2*)vb)[i] = o;
    } else if (b < NB_CONV + NB_WPREP) {
        int t = (b - NB_CONV) * 256 + threadIdx.x;   // 0..2047
        int lane = t & 63, nt = (t >> 6) & 7, kk = t >> 9;
        int n  = nt * 16 + (lane & 15);
        int k0 = kk * 32 + (lane >> 4) * 8;
        unsigned short h[8];
        #pragma unroll
        for (int i = 0; i < 8; ++i) h[i] = f2bf(Aw[n * DIM + k0 + i]);
        uint4 o;
        o.x = h[0] | ((unsigned)h[1] << 16); o.y = h[2] | ((unsigned)h[3] << 16);
        o.z = h[4] | ((unsigned)h[5] << 16); o.w = h[6] | ((unsigned)h[7] << 16);
        wfrag[t] = o;
    } else {
        int cb = b - NB_CONV - NB_WPREP;
        int beg = cb * CH_HIST, end = beg + CH_HIST;
        for (int i = beg + threadIdx.x; i < end; i += 256)
            atomicAdd(&hist[dst[i]], 1);         // 1.6M adds over 50K counters
    }
}

// ---------------- single-block exclusive scan over 50000 node counts -------
__global__ __launch_bounds__(1024) void kscan_node_kernel(
        const int* __restrict__ hist,
        int* __restrict__ off, int* __restrict__ ncur) {
    __shared__ int part[1024];
    int tid = threadIdx.x;
    const int CHK = (N_NODES + 1023) / 1024;     // 49
    int i0 = tid * CHK;
    int s = 0;
    for (int k = 0; k < CHK; ++k) {
        int i = i0 + k;
        if (i < N_NODES) s += hist[i];
    }
    part[tid] = s; __syncthreads();
    for (int d = 1; d < 1024; d <<= 1) {
        int val = (tid >= d) ? part[tid - d] : 0;
        __syncthreads(); part[tid] += val; __syncthreads();
    }
    int run = (tid == 0) ? 0 : part[tid - 1];
    for (int k = 0; k < CHK; ++k) {
        int i = i0 + k;
        if (i < N_NODES) { off[i] = run; ncur[i] = run; run += hist[i]; }
    }
    if (tid == 0) off[N_NODES] = N_EDGES;
}

// ---------------- reorder: envelope + direct node-exact CSR write ----------
__global__ __launch_bounds__(512) void reorder_kernel(
        const float* __restrict__ e,
        const int*   __restrict__ src,
        const int*   __restrict__ dst,
        const float* __restrict__ rs,
        const float* __restrict__ sigma,
        int*  __restrict__ ncur,
        int2* __restrict__ meta) {
    int b = blockIdx.x, tid = threadIdx.x;
    float rsv = rs[0], sg = sigma[0];
    int beg = b * CH_RE, end = beg + CH_RE;
    for (int i = beg + tid; i < end; i += 512) {
        float r  = e[i];
        float d  = r - rsv;
        float gauss = expf(-(d * d) / (sg * sg));
        float cut   = 0.5f * cosf(r * (float)(M_PI / (double)RCUT));
        cut = (r < RCUT) ? cut : 0.0f;
        float fe = gauss * cut;
        int dn = dst[i];
        int lr = atomicAdd(&ncur[dn], 1);        // global slot alloc (32/line avg)
        meta[lr] = make_int2(src[i] * (DIM * 2), __float_as_int(fe));
    }
}

// ---------------- shared gather inner loop ----------------
#define EDGE2(mx, mf, rr)                                        \
    do {                                                         \
        float ff = __int_as_float(mf);                           \
        a0 = fmaf(ff, bf_lo(rr), a0);                            \
        a1 = fmaf(ff, bf_hi(rr), a1);                            \
    } while (0)

__device__ __forceinline__ void gather_node(
        const int2* __restrict__ meta, const char* basec,
        int beg, int end, float& a0, float& a1) {
    int c = beg;
    if ((c & 1) && c < end) {
        int2 m = meta[c];
        unsigned rr = *(const unsigned*)(basec + (unsigned)m.x);
        EDGE2(m.x, m.y, rr);
        ++c;
    }
    for (; c + 16 <= end; c += 16) {
        int4 m0 = *(const int4*)(meta + c);
        int4 m1 = *(const int4*)(meta + c + 2);
        int4 m2 = *(const int4*)(meta + c + 4);
        int4 m3 = *(const int4*)(meta + c + 6);
        int4 m4 = *(const int4*)(meta + c + 8);
        int4 m5 = *(const int4*)(meta + c + 10);
        int4 m6 = *(const int4*)(meta + c + 12);
        int4 m7 = *(const int4*)(meta + c + 14);
        unsigned r0  = *(const unsigned*)(basec + (unsigned)m0.x);
        unsigned r1  = *(const unsigned*)(basec + (unsigned)m0.z);
        unsigned r2  = *(const unsigned*)(basec + (unsigned)m1.x);
        unsigned r3  = *(const unsigned*)(basec + (unsigned)m1.z);
        unsigned r4  = *(const unsigned*)(basec + (unsigned)m2.x);
        unsigned r5  = *(const unsigned*)(basec + (unsigned)m2.z);
        unsigned r6  = *(const unsigned*)(basec + (unsigned)m3.x);
        unsigned r7  = *(const unsigned*)(basec + (unsigned)m3.z);
        unsigned r8  = *(const unsigned*)(basec + (unsigned)m4.x);
        unsigned r9  = *(const unsigned*)(basec + (unsigned)m4.z);
        unsigned r10 = *(const unsigned*)(basec + (unsigned)m5.x);
        unsigned r11 = *(const unsigned*)(basec + (unsigned)m5.z);
        unsigned r12 = *(const unsigned*)(basec + (unsigned)m6.x);
        unsigned r13 = *(const unsigned*)(basec + (unsigned)m6.z);
        unsigned r14 = *(const unsigned*)(basec + (unsigned)m7.x);
        unsigned r15 = *(const unsigned*)(basec + (unsigned)m7.z);
        EDGE2(m0.x, m0.y, r0);  EDGE2(m0.z, m0.w, r1);
        EDGE2(m1.x, m1.y, r2);  EDGE2(m1.z, m1.w, r3);
        EDGE2(m2.x, m2.y, r4);  EDGE2(m2.z, m2.w, r5);
        EDGE2(m3.x, m3.y, r6);  EDGE2(m3.z, m3.w, r7);
        EDGE2(m4.x, m4.y, r8);  EDGE2(m4.z, m4.w, r9);
        EDGE2(m5.x, m5.y, r10); EDGE2(m5.z, m5.w, r11);
        EDGE2(m6.x, m6.y, r12); EDGE2(m6.z, m6.w, r13);
        EDGE2(m7.x, m7.y, r14); EDGE2(m7.z, m7.w, r15);
    }
    if (c + 8 <= end) {
        int4 m0 = *(const int4*)(meta + c);
        int4 m1 = *(const int4*)(meta + c + 2);
        int4 m2 = *(const int4*)(meta + c + 4);
        int4 m3 = *(const int4*)(meta + c + 6);
        unsigned r0 = *(const unsigned*)(basec + (unsigned)m0.x);
        unsigned r1 = *(const unsigned*)(basec + (unsigned)m0.z);
        unsigned r2 = *(const unsigned*)(basec + (unsigned)m1.x);
        unsigned r3 = *(const unsigned*)(basec + (unsigned)m1.z);
        unsigned r4 = *(const unsigned*)(basec + (unsigned)m2.x);
        unsigned r5 = *(const unsigned*)(basec + (unsigned)m2.z);
        unsigned r6 = *(const unsigned*)(basec + (unsigned)m3.x);
        unsigned r7 = *(const unsigned*)(basec + (unsigned)m3.z);
        EDGE2(m0.x, m0.y, r0); EDGE2(m0.z, m0.w, r1);
        EDGE2(m1.x, m1.y, r2); EDGE2(m1.z, m1.w, r3);
        EDGE2(m2.x, m2.y, r4); EDGE2(m2.z, m2.w, r5);
        EDGE2(m3.x, m3.y, r6); EDGE2(m3.z, m3.w, r7);
        c += 8;
    }
    for (; c < end; ++c) {
        int2 m = meta[c];
        unsigned rr = *(const unsigned*)(basec + (unsigned)m.x);
        EDGE2(m.x, m.y, rr);
    }
}

// ---------------- fused layer: 2-wave 16-node gather + GEMM ----------------
__global__ __launch_bounds__(128, 8) void layer_kernel(
        const unsigned short* __restrict__ cur,
        const unsigned short* __restrict__ vb,
        const int2*  __restrict__ meta,
        const int*   __restrict__ off,
        const uint4* __restrict__ wfrag,
        const float* __restrict__ bias,
        unsigned short* __restrict__ out_bf,
        float* __restrict__ out_f,
        int last) {
    __shared__ unsigned short xlds[16 * XPAD];    // 4352 B
    int tid = threadIdx.x;
    int wv  = tid >> 6, lane = tid & 63;          // wv in {0,1}
    int tile = blockIdx.x;
    int n0  = tile * 16 + wv * 8;

    int offidx = n0 + ((lane < 9) ? lane : 8);
    if (offidx > N_NODES) offidx = N_NODES;
    int myoff = off[offidx];
    const char* basec = (const char*)cur + lane * 4;

    #pragma unroll 1
    for (int q = 0; q < 8; ++q) {
        int nl = wv * 8 + q;
        int n  = n0 + q;
        float a0 = 0.f, a1 = 0.f;
        if (n < N_NODES) {
            unsigned vv = *(const unsigned*)((const char*)vb + (size_t)n * (DIM * 2) + lane * 4);
            a0 = bf_lo(vv); a1 = bf_hi(vv);
            int beg = __builtin_amdgcn_readlane(myoff, q);
            int end = __builtin_amdgcn_readlane(myoff, q + 1);
            gather_node(meta, basec, beg, end, a0, a1);
        }
        *(unsigned*)(xlds + nl * XPAD + lane * 2) =
            (unsigned)f2bf(a0) | ((unsigned)f2bf(a1) << 16);
    }
    __syncthreads();

    // ---- GEMM: both waves cover all 16 rows; wave = col-half ----
    int quad = lane >> 4, l16 = lane & 15;
    f32x4 acc[4];
    #pragma unroll
    for (int j = 0; j < 4; ++j) acc[j] = (f32x4){0.f, 0.f, 0.f, 0.f};

    const unsigned short* xp = xlds + l16 * XPAD + quad * 8;
    #pragma unroll
    for (int kk = 0; kk < 4; ++kk) {
        bf16x8 af = *(const bf16x8*)(xp + kk * 32);
        #pragma unroll
        for (int j = 0; j < 4; ++j) {
            uint4 w = wfrag[(kk * 8 + wv * 4 + j) * 64 + lane];
            bf16x8 bfr = __builtin_bit_cast(bf16x8, w);
            acc[j] = __builtin_amdgcn_mfma_f32_16x16x32_bf16(af, bfr, acc[j], 0, 0, 0);
        }
    }

    int orow0 = tile * 16 + quad * 4;
    #pragma unroll
    for (int j = 0; j < 4; ++j) {
        int col = (wv * 4 + j) * 16 + l16;
        float b = bias[col];
        #pragma unroll
        for (int r = 0; r < 4; ++r) {
            int orow = orow0 + r;
            if (orow < N_NODES) {
                float val = fmaxf(acc[j][r] + b, 0.f);
                if (last) out_f[(size_t)orow * DIM + col] = val;
                else      out_bf[(size_t)orow * DIM + col] = f2bf(val);
            }
        }
    }
}

// ---------------------------------------------------------------------------
extern "C" void kernel_launch(void* const* d_in, const int* in_sizes, int n_in,
                              void* d_out, int out_size, void* d_ws, size_t ws_size,
                              hipStream_t stream) {
    const float* v     = (const float*)d_in[0];
    const float* e     = (const float*)d_in[1];
    const int*   src   = (const int*)  d_in[2];
    const int*   dst   = (const int*)  d_in[3];
    const float* Aw    = (const float*)d_in[4];
    const float* Ab    = (const float*)d_in[5];
    const float* rs    = (const float*)d_in[6];
    const float* sigma = (const float*)d_in[7];
    float* out = (float*)d_out;

    // ---- workspace layout (~52 MB) ----
    char* p = (char*)d_ws;
    int2*           meta  = (int2*)p;            p += (size_t)N_EDGES * 8;       // 12.8 MB (node-exact CSR)
    unsigned short* bufV  = (unsigned short*)p;  p += (size_t)N_PAD * DIM * 2;   // 12.81 MB (pristine bf16 v)
    unsigned short* bufA  = (unsigned short*)p;  p += (size_t)N_PAD * DIM * 2;   // 12.81 MB (L1 out)
    unsigned short* bufB  = (unsigned short*)p;  p += (size_t)N_PAD * DIM * 2;   // 12.81 MB (L0 out)
    uint4*          wfrag = (uint4*)p;           p += 2048 * 16;                 //  32 KB
    int*            off   = (int*)p;             p += (size_t)(N_NODES + 2) * 4; // 200 KB
    int*            ncur  = (int*)p;             p += (size_t)N_NODES * 4;       // 200 KB
    int*            hist  = (int*)p;             p += (size_t)N_NODES * 4;       // 200 KB

    hipMemsetAsync(hist, 0, (size_t)N_NODES * 4, stream);
    // pre: v->bf16 | W frags | node histogram
    pre_kernel<<<NB_CONV + NB_WPREP + NB_HIST, 256, 0, stream>>>(
        v, bufV, Aw, wfrag, dst, hist);
    // exclusive scan -> off[] and working cursors ncur[]
    kscan_node_kernel<<<1, 1024, 0, stream>>>(hist, off, ncur);
    // envelope + direct node-exact CSR
    reorder_kernel<<<NB_RE, 512, 0, stream>>>(e, src, dst, rs, sigma, ncur, meta);

    // three fused gather+GEMM layers (same kernel)
    layer_kernel<<<NTILE, 128, 0, stream>>>(
        bufV, bufV, meta, off, wfrag, Ab, bufB, nullptr, 0);
    layer_kernel<<<NTILE, 128, 0, stream>>>(
        bufB, bufV, meta, off, wfrag, Ab, bufA, nullptr, 0);
    layer_kernel<<<NTILE, 128, 0, stream>>>(
        bufA, bufV, meta, off, wfrag, Ab, nullptr, out, 1);
}

// Round 6
// 371.056 us; speedup vs baseline: 1.5883x; 1.5883x over previous
//
#include <hip/hip_runtime.h>
#include <math.h>

#define N_NODES 50000
#define N_PAD   50048              // rows padded to multiple of 64
#define N_EDGES 1600000
#define DIM     128
#define RCUT    5.0f
#define NGROUP  (N_PAD / 64)       // 782 groups of 64 nodes
#define NB_CONV 6250               // convert blocks in pre
#define NB_WPREP 8                 // wprep blocks in pre
#define NB_HIST 512                // histogram blocks in pre
#define CH_HIST (N_EDGES / NB_HIST)
#define NB_RE   512                // reorder blocks
#define CH_RE   (N_EDGES / NB_RE)
#define XPAD    136                // LDS X tile row stride in bf16 (272 B)
#define NTILE   (N_PAD / 16)       // 3128 16-node tiles for layer12
#define GPAD    32                 // ints per padded group counter (128 B line)

typedef __attribute__((ext_vector_type(8))) __bf16 bf16x8;
typedef __attribute__((ext_vector_type(4))) float  f32x4;

// ---------------- bf16 helpers ----------------
__device__ __forceinline__ float bf_lo(unsigned int u) { return __uint_as_float(u << 16); }
__device__ __forceinline__ float bf_hi(unsigned int u) { return __uint_as_float(u & 0xffff0000u); }
__device__ __forceinline__ unsigned short f2bf(float x) {
    unsigned int u = __float_as_uint(x);
    u += 0x7fffu + ((u >> 16) & 1u);   // round-to-nearest-even
    return (unsigned short)(u >> 16);
}

// ---------------- pre: v->bf16 | W->frags | group totals (padded atomics) ---
__global__ __launch_bounds__(256) void pre_kernel(
        const float* __restrict__ v, unsigned short* __restrict__ vb,
        const float* __restrict__ Aw, uint4* __restrict__ wfrag,
        const int* __restrict__ dst, int* __restrict__ gtotP) {
    int b = blockIdx.x;
    if (b < NB_CONV) {
        int i = b * 256 + threadIdx.x;           // exactly N_NODES*DIM/4
        float4 x = ((const float4*)v)[i];
        uint2 o;
        o.x = (unsigned)f2bf(x.x) | ((unsigned)f2bf(x.y) << 16);
        o.y = (unsigned)f2bf(x.z) | ((unsigned)f2bf(x.w) << 16);
        ((uint2*)vb)[i] = o;
    } else if (b < NB_CONV + NB_WPREP) {
        int t = (b - NB_CONV) * 256 + threadIdx.x;   // 0..2047
        int lane = t & 63, nt = (t >> 6) & 7, kk = t >> 9;
        int n  = nt * 16 + (lane & 15);
        int k0 = kk * 32 + (lane >> 4) * 8;
        unsigned short h[8];
        #pragma unroll
        for (int i = 0; i < 8; ++i) h[i] = f2bf(Aw[n * DIM + k0 + i]);
        uint4 o;
        o.x = h[0] | ((unsigned)h[1] << 16); o.y = h[2] | ((unsigned)h[3] << 16);
        o.z = h[4] | ((unsigned)h[5] << 16); o.w = h[6] | ((unsigned)h[7] << 16);
        wfrag[t] = o;
    } else {
        __shared__ int h[NGROUP];                // 3.1 KB
        int cb = b - NB_CONV - NB_WPREP, tid = threadIdx.x;
        for (int g = tid; g < NGROUP; g += 256) h[g] = 0;
        __syncthreads();
        int beg = cb * CH_HIST, end = beg + CH_HIST;
        for (int i = beg + tid; i < end; i += 256)
            atomicAdd(&h[dst[i] >> 6], 1);       // LDS atomic
        __syncthreads();
        for (int g = tid; g < NGROUP; g += 256)
            if (h[g]) atomicAdd(&gtotP[g * GPAD], h[g]);  // 1 private line/group
    }
}

// ---------------- exclusive scan over 782 group totals -> goff, gcurP ------
__global__ __launch_bounds__(256) void kscan_kernel(const int* __restrict__ gtotP,
                                                    int* __restrict__ goff,
                                                    int* __restrict__ gcurP) {
    __shared__ int part[256];
    int tid = threadIdx.x;
    int i0 = tid * 4;
    int v[4]; int s = 0;
    #pragma unroll
    for (int k = 0; k < 4; ++k) {
        int i = i0 + k;
        v[k] = (i < NGROUP) ? gtotP[i * GPAD] : 0; s += v[k];
    }
    part[tid] = s; __syncthreads();
    for (int d = 1; d < 256; d <<= 1) {
        int val = (tid >= d) ? part[tid - d] : 0;
        __syncthreads(); part[tid] += val; __syncthreads();
    }
    int run = (tid == 0) ? 0 : part[tid - 1];
    #pragma unroll
    for (int k = 0; k < 4; ++k) {
        int i = i0 + k;
        if (i < NGROUP) { goff[i] = run; gcurP[i * GPAD] = run; run += v[k]; }
    }
    if (tid == 0) goff[NGROUP] = N_EDGES;
}

// ---------------- reorder: count chunk, batch-claim regions, scatter -------
__global__ __launch_bounds__(512) void reorder_kernel(
        const float* __restrict__ e,
        const int*   __restrict__ src,
        const int*   __restrict__ dst,
        const float* __restrict__ rs,
        const float* __restrict__ sigma,
        int*  __restrict__ gcurP,
        int2* __restrict__ metaT) {
    __shared__ int base[NGROUP];
    __shared__ int cnt[NGROUP];
    int b = blockIdx.x, tid = threadIdx.x;
    for (int g = tid; g < NGROUP; g += 512) cnt[g] = 0;
    __syncthreads();
    int beg = b * CH_RE, end = beg + CH_RE;
    // pass 1: local group histogram of this chunk
    for (int i = beg + tid; i < end; i += 512)
        atomicAdd(&cnt[dst[i] >> 6], 1);
    __syncthreads();
    // batch-claim a dense region per group (1 atomic per (block,group))
    for (int g = tid; g < NGROUP; g += 512) {
        int c = cnt[g];
        base[g] = c ? atomicAdd(&gcurP[g * GPAD], c) : 0;
        cnt[g] = 0;
    }
    __syncthreads();
    float rsv = rs[0], sg = sigma[0];
    // pass 2: envelope + dense scatter into claimed regions
    for (int i = beg + tid; i < end; i += 512) {
        float r  = e[i];
        float d  = r - rsv;
        float gauss = expf(-(d * d) / (sg * sg));
        float cut   = 0.5f * cosf(r * (float)(M_PI / (double)RCUT));
        cut = (r < RCUT) ? cut : 0.0f;
        float fe = gauss * cut;
        int dn = dst[i];
        int g  = dn >> 6;
        int lr = atomicAdd(&cnt[g], 1);          // LDS atomic
        metaT[base[g] + lr] = make_int2(src[i] * (DIM * 2) | ((dn & 63) << 24),
                                        __float_as_int(fe));
    }
}

// ---------------- shared gather inner loop ----------------
#define EDGE2(mx, mf, rr)                                        \
    do {                                                         \
        float ff = __int_as_float(mf);                           \
        a0 = fmaf(ff, bf_lo(rr), a0);                            \
        a1 = fmaf(ff, bf_hi(rr), a1);                            \
    } while (0)

__device__ __forceinline__ void gather_node(
        const int2* __restrict__ meta, const char* basec,
        int beg, int end, float& a0, float& a1) {
    int c = beg;
    if ((c & 1) && c < end) {
        int2 m = meta[c];
        unsigned rr = *(const unsigned*)(basec + (unsigned)m.x);
        EDGE2(m.x, m.y, rr);
        ++c;
    }
    for (; c + 16 <= end; c += 16) {
        int4 m0 = *(const int4*)(meta + c);
        int4 m1 = *(const int4*)(meta + c + 2);
        int4 m2 = *(const int4*)(meta + c + 4);
        int4 m3 = *(const int4*)(meta + c + 6);
        int4 m4 = *(const int4*)(meta + c + 8);
        int4 m5 = *(const int4*)(meta + c + 10);
        int4 m6 = *(const int4*)(meta + c + 12);
        int4 m7 = *(const int4*)(meta + c + 14);
        unsigned r0  = *(const unsigned*)(basec + (unsigned)m0.x);
        unsigned r1  = *(const unsigned*)(basec + (unsigned)m0.z);
        unsigned r2  = *(const unsigned*)(basec + (unsigned)m1.x);
        unsigned r3  = *(const unsigned*)(basec + (unsigned)m1.z);
        unsigned r4  = *(const unsigned*)(basec + (unsigned)m2.x);
        unsigned r5  = *(const unsigned*)(basec + (unsigned)m2.z);
        unsigned r6  = *(const unsigned*)(basec + (unsigned)m3.x);
        unsigned r7  = *(const unsigned*)(basec + (unsigned)m3.z);
        unsigned r8  = *(const unsigned*)(basec + (unsigned)m4.x);
        unsigned r9  = *(const unsigned*)(basec + (unsigned)m4.z);
        unsigned r10 = *(const unsigned*)(basec + (unsigned)m5.x);
        unsigned r11 = *(const unsigned*)(basec + (unsigned)m5.z);
        unsigned r12 = *(const unsigned*)(basec + (unsigned)m6.x);
        unsigned r13 = *(const unsigned*)(basec + (unsigned)m6.z);
        unsigned r14 = *(const unsigned*)(basec + (unsigned)m7.x);
        unsigned r15 = *(const unsigned*)(basec + (unsigned)m7.z);
        EDGE2(m0.x, m0.y, r0);  EDGE2(m0.z, m0.w, r1);
        EDGE2(m1.x, m1.y, r2);  EDGE2(m1.z, m1.w, r3);
        EDGE2(m2.x, m2.y, r4);  EDGE2(m2.z, m2.w, r5);
        EDGE2(m3.x, m3.y, r6);  EDGE2(m3.z, m3.w, r7);
        EDGE2(m4.x, m4.y, r8);  EDGE2(m4.z, m4.w, r9);
        EDGE2(m5.x, m5.y, r10); EDGE2(m5.z, m5.w, r11);
        EDGE2(m6.x, m6.y, r12); EDGE2(m6.z, m6.w, r13);
        EDGE2(m7.x, m7.y, r14); EDGE2(m7.z, m7.w, r15);
    }
    if (c + 8 <= end) {
        int4 m0 = *(const int4*)(meta + c);
        int4 m1 = *(const int4*)(meta + c + 2);
        int4 m2 = *(const int4*)(meta + c + 4);
        int4 m3 = *(const int4*)(meta + c + 6);
        unsigned r0 = *(const unsigned*)(basec + (unsigned)m0.x);
        unsigned r1 = *(const unsigned*)(basec + (unsigned)m0.z);
        unsigned r2 = *(const unsigned*)(basec + (unsigned)m1.x);
        unsigned r3 = *(const unsigned*)(basec + (unsigned)m1.z);
        unsigned r4 = *(const unsigned*)(basec + (unsigned)m2.x);
        unsigned r5 = *(const unsigned*)(basec + (unsigned)m2.z);
        unsigned r6 = *(const unsigned*)(basec + (unsigned)m3.x);
        unsigned r7 = *(const unsigned*)(basec + (unsigned)m3.z);
        EDGE2(m0.x, m0.y, r0); EDGE2(m0.z, m0.w, r1);
        EDGE2(m1.x, m1.y, r2); EDGE2(m1.z, m1.w, r3);
        EDGE2(m2.x, m2.y, r4); EDGE2(m2.z, m2.w, r5);
        EDGE2(m3.x, m3.y, r6); EDGE2(m3.z, m3.w, r7);
        c += 8;
    }
    for (; c < end; ++c) {
        int2 m = meta[c];
        unsigned rr = *(const unsigned*)(basec + (unsigned)m.x);
        EDGE2(m.x, m.y, rr);
    }
}

// ---------------- layer 0: per-wave tagsort + gather + GEMM ----------------
__global__ __launch_bounds__(512) void layer0_kernel(
        const unsigned short* __restrict__ cur,   // bf16 (= vb for L0)
        const unsigned short* __restrict__ vb,
        const int2*  __restrict__ metaT,          // group-CSR, tagged
        const int*   __restrict__ goff,
        int2* __restrict__ meta,                  // out: node-exact CSR
        int*  __restrict__ off,                   // out: node offsets
        const uint4* __restrict__ wfrag,
        const float* __restrict__ bias,
        unsigned short* __restrict__ out_bf) {
    __shared__ unsigned short xlds[64 * XPAD];    // 17408 B
    __shared__ int cnt8[8][64];                   // per-wave tag counts
    __shared__ int wcur[8][64];                   // per-wave scatter cursors
    __shared__ int b64[65];
    int tid = threadIdx.x;
    int wv  = tid >> 6, lane = tid & 63;
    int g   = blockIdx.x;
    int sbeg = goff[g], send = goff[g + 1];

    // ---- per-wave 64-bin count ----
    ((int*)cnt8)[tid] = 0;                        // 512 ints exactly
    __syncthreads();
    for (int i = sbeg + tid; i < send; i += 512)
        atomicAdd(&cnt8[wv][(metaT[i].x >> 24) & 63], 1);
    __syncthreads();
    // ---- wave-parallel scan over tags + per-wave bases ----
    if (tid < 64) {
        int x = 0;
        #pragma unroll
        for (int w = 0; w < 8; ++w) x += cnt8[w][tid];
        int incl = x;
        #pragma unroll
        for (int d = 1; d < 64; d <<= 1) {
            int y = __shfl_up(incl, d, 64);
            if (tid >= d) incl += y;
        }
        int excl = incl - x;
        b64[tid] = excl;
        if (tid == 63) b64[64] = incl;
        int run = excl;
        #pragma unroll
        for (int w = 0; w < 8; ++w) { wcur[w][tid] = run; run += cnt8[w][tid]; }
        int node = g * 64 + tid;
        if (node <= N_NODES) off[node] = sbeg + excl;
    }
    __syncthreads();
    // ---- scatter into node-exact meta (per-wave cursors) ----
    for (int i = sbeg + tid; i < send; i += 512) {
        int2 m = metaT[i];
        int tag = (m.x >> 24) & 63;
        int lr = atomicAdd(&wcur[wv][tag], 1);
        meta[sbeg + lr] = make_int2(m.x & 0x00FFFFFF, m.y);
    }
    __syncthreads();   // meta writes issued; b64 stable

    // ---- gather (offsets from LDS b64) ----
    int n0 = g * 64 + wv * 8;
    int myoff = 0;
    if (lane < 9) myoff = sbeg + b64[wv * 8 + lane];
    const char* basec = (const char*)cur + lane * 4;

    #pragma unroll 1
    for (int q = 0; q < 8; ++q) {
        int nl = wv * 8 + q;
        int n  = n0 + q;
        float a0 = 0.f, a1 = 0.f;
        if (n < N_NODES) {
            unsigned vv = *(const unsigned*)((const char*)vb + (size_t)n * (DIM * 2) + lane * 4);
            a0 = bf_lo(vv); a1 = bf_hi(vv);
            int beg = __builtin_amdgcn_readlane(myoff, q);
            int end = __builtin_amdgcn_readlane(myoff, q + 1);
            gather_node(meta, basec, beg, end, a0, a1);
        }
        *(unsigned*)(xlds + nl * XPAD + lane * 2) =
            (unsigned)f2bf(a0) | ((unsigned)f2bf(a1) << 16);
    }
    __syncthreads();

    // ---- GEMM: wave wv -> rows (wv>>1)*16..+15, col-half (wv&1) ----
    int quad = lane >> 4, l16 = lane & 15;
    int rb = wv >> 1, nh = wv & 1;
    f32x4 acc[4];
    #pragma unroll
    for (int j = 0; j < 4; ++j) acc[j] = (f32x4){0.f, 0.f, 0.f, 0.f};

    const unsigned short* xp = xlds + (rb * 16 + l16) * XPAD + quad * 8;
    #pragma unroll
    for (int kk = 0; kk < 4; ++kk) {
        bf16x8 af = *(const bf16x8*)(xp + kk * 32);
        #pragma unroll
        for (int j = 0; j < 4; ++j) {
            uint4 w = wfrag[(kk * 8 + nh * 4 + j) * 64 + lane];
            bf16x8 bfr = __builtin_bit_cast(bf16x8, w);
            acc[j] = __builtin_amdgcn_mfma_f32_16x16x32_bf16(af, bfr, acc[j], 0, 0, 0);
        }
    }

    int orow0 = g * 64 + rb * 16 + quad * 4;
    #pragma unroll
    for (int j = 0; j < 4; ++j) {
        int col = (nh * 4 + j) * 16 + l16;
        float b = bias[col];
        #pragma unroll
        for (int r = 0; r < 4; ++r) {
            int orow = orow0 + r;
            if (orow < N_NODES)
                out_bf[(size_t)orow * DIM + col] = f2bf(fmaxf(acc[j][r] + b, 0.f));
        }
    }
}

// ---------------- layers 1/2: 2-wave 16-node fused gather+GEMM -------------
__global__ __launch_bounds__(128, 8) void layer12_kernel(
        const unsigned short* __restrict__ cur,
        const unsigned short* __restrict__ vb,
        const int2*  __restrict__ meta,
        const int*   __restrict__ off,
        const uint4* __restrict__ wfrag,
        const float* __restrict__ bias,
        unsigned short* __restrict__ out_bf,
        float* __restrict__ out_f,
        int last) {
    __shared__ unsigned short xlds[16 * XPAD];    // 4352 B
    int tid = threadIdx.x;
    int wv  = tid >> 6, lane = tid & 63;          // wv in {0,1}
    int tile = blockIdx.x;
    int n0  = tile * 16 + wv * 8;

    int offidx = n0 + ((lane < 9) ? lane : 8);
    if (offidx > N_NODES) offidx = N_NODES;
    int myoff = off[offidx];
    const char* basec = (const char*)cur + lane * 4;

    #pragma unroll 1
    for (int q = 0; q < 8; ++q) {
        int nl = wv * 8 + q;
        int n  = n0 + q;
        float a0 = 0.f, a1 = 0.f;
        if (n < N_NODES) {
            unsigned vv = *(const unsigned*)((const char*)vb + (size_t)n * (DIM * 2) + lane * 4);
            a0 = bf_lo(vv); a1 = bf_hi(vv);
            int beg = __builtin_amdgcn_readlane(myoff, q);
            int end = __builtin_amdgcn_readlane(myoff, q + 1);
            gather_node(meta, basec, beg, end, a0, a1);
        }
        *(unsigned*)(xlds + nl * XPAD + lane * 2) =
            (unsigned)f2bf(a0) | ((unsigned)f2bf(a1) << 16);
    }
    __syncthreads();

    // ---- GEMM: both waves cover all 16 rows; wave = col-half ----
    int quad = lane >> 4, l16 = lane & 15;
    f32x4 acc[4];
    #pragma unroll
    for (int j = 0; j < 4; ++j) acc[j] = (f32x4){0.f, 0.f, 0.f, 0.f};

    const unsigned short* xp = xlds + l16 * XPAD + quad * 8;
    #pragma unroll
    for (int kk = 0; kk < 4; ++kk) {
        bf16x8 af = *(const bf16x8*)(xp + kk * 32);
        #pragma unroll
        for (int j = 0; j < 4; ++j) {
            uint4 w = wfrag[(kk * 8 + wv * 4 + j) * 64 + lane];
            bf16x8 bfr = __builtin_bit_cast(bf16x8, w);
            acc[j] = __builtin_amdgcn_mfma_f32_16x16x32_bf16(af, bfr, acc[j], 0, 0, 0);
        }
    }

    int orow0 = tile * 16 + quad * 4;
    #pragma unroll
    for (int j = 0; j < 4; ++j) {
        int col = (wv * 4 + j) * 16 + l16;
        float b = bias[col];
        #pragma unroll
        for (int r = 0; r < 4; ++r) {
            int orow = orow0 + r;
            if (orow < N_NODES) {
                float val = fmaxf(acc[j][r] + b, 0.f);
                if (last) out_f[(size_t)orow * DIM + col] = val;
                else      out_bf[(size_t)orow * DIM + col] = f2bf(val);
            }
        }
    }
}

// ---------------------------------------------------------------------------
extern "C" void kernel_launch(void* const* d_in, const int* in_sizes, int n_in,
                              void* d_out, int out_size, void* d_ws, size_t ws_size,
                              hipStream_t stream) {
    const float* v     = (const float*)d_in[0];
    const float* e     = (const float*)d_in[1];
    const int*   src   = (const int*)  d_in[2];
    const int*   dst   = (const int*)  d_in[3];
    const float* Aw    = (const float*)d_in[4];
    const float* Ab    = (const float*)d_in[5];
    const float* rs    = (const float*)d_in[6];
    const float* sigma = (const float*)d_in[7];
    float* out = (float*)d_out;

    // ---- workspace layout (~51.7 MB) ----
    char* p = (char*)d_ws;
    int2*           meta  = (int2*)p;            p += (size_t)N_EDGES * 8;       // 12.8 MB (node-exact CSR)
    unsigned short* bufV  = (unsigned short*)p;  p += (size_t)N_PAD * DIM * 2;   // 12.81 MB (pristine bf16 v)
    unsigned short* bufA  = (unsigned short*)p;  p += (size_t)N_PAD * DIM * 2;   // 12.81 MB (metaT / L1 out)
    unsigned short* bufB  = (unsigned short*)p;  p += (size_t)N_PAD * DIM * 2;   // 12.81 MB (L0 out)
    uint4*          wfrag = (uint4*)p;           p += 2048 * 16;                 //  32 KB
    int*            off   = (int*)p;             p += (size_t)(N_NODES + 2) * 4; // 200 KB
    int*            goff  = (int*)p;             p += (NGROUP + 2) * 4;          //   3 KB
    int*            gtotP = (int*)p;             p += NGROUP * GPAD * 4;         // 100 KB padded totals
    int*            gcurP = (int*)p;             p += NGROUP * GPAD * 4;         // 100 KB padded cursors
    // alias (dead before bufA's first real write):
    int2* metaT = (int2*)bufA;                   // unsorted group-CSR, dead after layer0

    hipMemsetAsync(gtotP, 0, NGROUP * GPAD * 4, stream);
    // pre: v->bf16 | W frags | group totals
    pre_kernel<<<NB_CONV + NB_WPREP + NB_HIST, 256, 0, stream>>>(
        v, bufV, Aw, wfrag, dst, gtotP);
    // scan group totals -> goff + padded cursors
    kscan_kernel<<<1, 256, 0, stream>>>(gtotP, goff, gcurP);
    // reorder: count, batch-claim group regions, dense scatter (tagged)
    reorder_kernel<<<NB_RE, 512, 0, stream>>>(e, src, dst, rs, sigma, gcurP, metaT);

    // L0: per-wave tagsort + gather(bufV) + gemm -> bufB  (consumes metaT)
    layer0_kernel<<<NGROUP, 512, 0, stream>>>(
        bufV, bufV, metaT, goff, meta, off, wfrag, Ab, bufB);
    // L1: gather(bufB) + gemm -> bufA
    layer12_kernel<<<NTILE, 128, 0, stream>>>(
        bufB, bufV, meta, off, wfrag, Ab, bufA, nullptr, 0);
    // L2: gather(bufA) + gemm -> out (fp32)
    layer12_kernel<<<NTILE, 128, 0, stream>>>(
        bufA, bufV, meta, off, wfrag, Ab, nullptr, out, 1);
}

// Round 7
// 361.036 us; speedup vs baseline: 1.6324x; 1.0278x over previous
//
#include <hip/hip_runtime.h>
#include <math.h>

#define N_NODES 50000
#define N_PAD   50048              // rows padded to multiple of 64
#define N_EDGES 1600000
#define DIM     128
#define RCUT    5.0f
#define NGROUP  (N_PAD / 64)       // 782 groups of 64 nodes
#define NB_PRE  512
#define CH_PRE  (N_EDGES / NB_PRE) // 3125 edges per preA histogram chunk
#define NB_CONV 6250               // convert blocks in preA
#define NB_WPREP 8                 // wprep blocks in preA
#define NB_SUB  8                  // b-subchunks for ktot2/kbase2
#define B_SUB   (NB_PRE / NB_SUB)  // 64
#define NB_RE   128                // reorder blocks (4 preA chunks each)
#define CH_RE   (N_EDGES / NB_RE)  // 12500 edges per reorder block
#define XPAD    136                // LDS X tile row stride in bf16 (272 B)

typedef __attribute__((ext_vector_type(8))) __bf16 bf16x8;
typedef __attribute__((ext_vector_type(4))) float  f32x4;

// ---------------- bf16 helpers ----------------
__device__ __forceinline__ float bf_lo(unsigned int u) { return __uint_as_float(u << 16); }
__device__ __forceinline__ float bf_hi(unsigned int u) { return __uint_as_float(u & 0xffff0000u); }
__device__ __forceinline__ unsigned short f2bf(float x) {
    unsigned int u = __float_as_uint(x);
    u += 0x7fffu + ((u >> 16) & 1u);   // round-to-nearest-even
    return (unsigned short)(u >> 16);
}

// ---------------- preA: convert v->bf16  |  W->frags  |  group-64 histogram ---
__global__ __launch_bounds__(256) void preA_kernel(
        const float* __restrict__ v, unsigned short* __restrict__ vb,
        const float* __restrict__ Aw, uint4* __restrict__ wfrag,
        const int* __restrict__ dst, int* __restrict__ partial) {
    int b = blockIdx.x;
    if (b < NB_CONV) {
        int i = b * 256 + threadIdx.x;           // exactly N_NODES*DIM/4
        float4 x = ((const float4*)v)[i];
        uint2 o;
        o.x = (unsigned)f2bf(x.x) | ((unsigned)f2bf(x.y) << 16);
        o.y = (unsigned)f2bf(x.z) | ((unsigned)f2bf(x.w) << 16);
        ((uint2*)vb)[i] = o;
    } else if (b < NB_CONV + NB_WPREP) {
        int t = (b - NB_CONV) * 256 + threadIdx.x;   // 0..2047
        int lane = t & 63, nt = (t >> 6) & 7, kk = t >> 9;
        int n  = nt * 16 + (lane & 15);
        int k0 = kk * 32 + (lane >> 4) * 8;
        unsigned short h[8];
        #pragma unroll
        for (int i = 0; i < 8; ++i) h[i] = f2bf(Aw[n * DIM + k0 + i]);
        uint4 o;
        o.x = h[0] | ((unsigned)h[1] << 16); o.y = h[2] | ((unsigned)h[3] << 16);
        o.z = h[4] | ((unsigned)h[5] << 16); o.w = h[6] | ((unsigned)h[7] << 16);
        wfrag[t] = o;
    } else {
        __shared__ int h[NGROUP];                // 3.1 KB
        int cb = b - NB_CONV - NB_WPREP, tid = threadIdx.x;
        for (int g = tid; g < NGROUP; g += 256) h[g] = 0;
        __syncthreads();
        int beg = cb * CH_PRE, end = beg + CH_PRE;
        for (int i = beg + tid; i < end; i += 256)
            atomicAdd(&h[dst[i] >> 6], 1);       // LDS atomic
        __syncthreads();
        for (int g = tid; g < NGROUP; g += 256) partial[cb * NGROUP + g] = h[g];
    }
}

// ---------------- partial sums over b-subchunks ----------------
__global__ __launch_bounds__(256) void ktot2_kernel(const int* __restrict__ partial,
                                                    int* __restrict__ partial2) {
    int gb = blockIdx.x & 3, bb = blockIdx.x >> 2;
    int g = gb * 256 + threadIdx.x;
    if (g >= NGROUP) return;
    int s = 0;
    int b0 = bb * B_SUB;
    for (int b = b0; b < b0 + B_SUB; ++b) s += partial[b * NGROUP + g];
    partial2[bb * NGROUP + g] = s;
}

// ---------------- exclusive scan over 782 group totals ----------------
__global__ __launch_bounds__(256) void kscan_kernel(const int* __restrict__ partial2,
                                                    int* __restrict__ goff) {
    __shared__ int part[256];
    int tid = threadIdx.x;
    int i0 = tid * 4;
    int v[4]; int s = 0;
    #pragma unroll
    for (int k = 0; k < 4; ++k) {
        int i = i0 + k; int t = 0;
        if (i < NGROUP) {
            #pragma unroll
            for (int bb = 0; bb < NB_SUB; ++bb) t += partial2[bb * NGROUP + i];
        }
        v[k] = t; s += t;
    }
    part[tid] = s; __syncthreads();
    for (int d = 1; d < 256; d <<= 1) {
        int val = (tid >= d) ? part[tid - d] : 0;
        __syncthreads(); part[tid] += val; __syncthreads();
    }
    int run = (tid == 0) ? 0 : part[tid - 1];
    #pragma unroll
    for (int k = 0; k < 4; ++k) {
        int i = i0 + k;
        if (i < NGROUP) { goff[i] = run; run += v[k]; }
    }
    if (tid == 0) goff[NGROUP] = N_EDGES;
}

// ---------------- per-(block,group) bases ----------------
__global__ __launch_bounds__(256) void kbase2_kernel(const int* __restrict__ partial,
                                                     const int* __restrict__ partial2,
                                                     const int* __restrict__ goff,
                                                     int* __restrict__ pbase) {
    int gb = blockIdx.x & 3, bb = blockIdx.x >> 2;
    int g = gb * 256 + threadIdx.x;
    if (g >= NGROUP) return;
    int run = goff[g];
    for (int b2 = 0; b2 < bb; ++b2) run += partial2[b2 * NGROUP + g];
    int b0 = bb * B_SUB;
    for (int b = b0; b < b0 + B_SUB; ++b) {
        pbase[b * NGROUP + g] = run;
        run += partial[b * NGROUP + g];
    }
}

// ---------------- reorder into group-64 CSR with 6-bit node tags ----------
// 128 blocks x 12500 edges: per-(block,group) runs avg 16 edges (128 B) ->
// ~2x less scattered-write line amplification than 512-block version.
__global__ __launch_bounds__(512) void reorder_kernel(
        const float* __restrict__ e,
        const int*   __restrict__ src,
        const int*   __restrict__ dst,
        const float* __restrict__ rs,
        const float* __restrict__ sigma,
        const int*   __restrict__ pbase,
        int2* __restrict__ metaT) {
    __shared__ int base[NGROUP];
    __shared__ int cnt[NGROUP];
    int b = blockIdx.x, tid = threadIdx.x;
    // block b's region per group starts at preA-chunk 4b's base (contiguous
    // through chunk 4b+3 since pbase runs in chunk order)
    for (int g = tid; g < NGROUP; g += 512) {
        base[g] = pbase[(b * 4) * NGROUP + g]; cnt[g] = 0;
    }
    __syncthreads();
    float rsv = rs[0], sg = sigma[0];
    int beg = b * CH_RE, end = beg + CH_RE;
    for (int i = beg + tid; i < end; i += 512) {
        float r  = e[i];
        float d  = r - rsv;
        float gauss = expf(-(d * d) / (sg * sg));
        float cut   = 0.5f * cosf(r * (float)(M_PI / (double)RCUT));
        cut = (r < RCUT) ? cut : 0.0f;
        float fe = gauss * cut;
        int dn = dst[i];
        int g  = dn >> 6;
        int lr = atomicAdd(&cnt[g], 1);          // LDS atomic
        metaT[base[g] + lr] = make_int2(src[i] * (DIM * 2) | ((dn & 63) << 24),
                                        __float_as_int(fe));
    }
}

// ---------------- shared gather inner loop ----------------
#define EDGE2(mx, mf, rr)                                        \
    do {                                                         \
        float ff = __int_as_float(mf);                           \
        a0 = fmaf(ff, bf_lo(rr), a0);                            \
        a1 = fmaf(ff, bf_hi(rr), a1);                            \
    } while (0)

__device__ __forceinline__ void gather_node(
        const int2* __restrict__ meta, const char* basec,
        int beg, int end, float& a0, float& a1) {
    int c = beg;
    if ((c & 1) && c < end) {
        int2 m = meta[c];
        unsigned rr = *(const unsigned*)(basec + (unsigned)m.x);
        EDGE2(m.x, m.y, rr);
        ++c;
    }
    for (; c + 16 <= end; c += 16) {
        int4 m0 = *(const int4*)(meta + c);
        int4 m1 = *(const int4*)(meta + c + 2);
        int4 m2 = *(const int4*)(meta + c + 4);
        int4 m3 = *(const int4*)(meta + c + 6);
        int4 m4 = *(const int4*)(meta + c + 8);
        int4 m5 = *(const int4*)(meta + c + 10);
        int4 m6 = *(const int4*)(meta + c + 12);
        int4 m7 = *(const int4*)(meta + c + 14);
        unsigned r0  = *(const unsigned*)(basec + (unsigned)m0.x);
        unsigned r1  = *(const unsigned*)(basec + (unsigned)m0.z);
        unsigned r2  = *(const unsigned*)(basec + (unsigned)m1.x);
        unsigned r3  = *(const unsigned*)(basec + (unsigned)m1.z);
        unsigned r4  = *(const unsigned*)(basec + (unsigned)m2.x);
        unsigned r5  = *(const unsigned*)(basec + (unsigned)m2.z);
        unsigned r6  = *(const unsigned*)(basec + (unsigned)m3.x);
        unsigned r7  = *(const unsigned*)(basec + (unsigned)m3.z);
        unsigned r8  = *(const unsigned*)(basec + (unsigned)m4.x);
        unsigned r9  = *(const unsigned*)(basec + (unsigned)m4.z);
        unsigned r10 = *(const unsigned*)(basec + (unsigned)m5.x);
        unsigned r11 = *(const unsigned*)(basec + (unsigned)m5.z);
        unsigned r12 = *(const unsigned*)(basec + (unsigned)m6.x);
        unsigned r13 = *(const unsigned*)(basec + (unsigned)m6.z);
        unsigned r14 = *(const unsigned*)(basec + (unsigned)m7.x);
        unsigned r15 = *(const unsigned*)(basec + (unsigned)m7.z);
        EDGE2(m0.x, m0.y, r0);  EDGE2(m0.z, m0.w, r1);
        EDGE2(m1.x, m1.y, r2);  EDGE2(m1.z, m1.w, r3);
        EDGE2(m2.x, m2.y, r4);  EDGE2(m2.z, m2.w, r5);
        EDGE2(m3.x, m3.y, r6);  EDGE2(m3.z, m3.w, r7);
        EDGE2(m4.x, m4.y, r8);  EDGE2(m4.z, m4.w, r9);
        EDGE2(m5.x, m5.y, r10); EDGE2(m5.z, m5.w, r11);
        EDGE2(m6.x, m6.y, r12); EDGE2(m6.z, m6.w, r13);
        EDGE2(m7.x, m7.y, r14); EDGE2(m7.z, m7.w, r15);
    }
    if (c + 8 <= end) {
        int4 m0 = *(const int4*)(meta + c);
        int4 m1 = *(const int4*)(meta + c + 2);
        int4 m2 = *(const int4*)(meta + c + 4);
        int4 m3 = *(const int4*)(meta + c + 6);
        unsigned r0 = *(const unsigned*)(basec + (unsigned)m0.x);
        unsigned r1 = *(const unsigned*)(basec + (unsigned)m0.z);
        unsigned r2 = *(const unsigned*)(basec + (unsigned)m1.x);
        unsigned r3 = *(const unsigned*)(basec + (unsigned)m1.z);
        unsigned r4 = *(const unsigned*)(basec + (unsigned)m2.x);
        unsigned r5 = *(const unsigned*)(basec + (unsigned)m2.z);
        unsigned r6 = *(const unsigned*)(basec + (unsigned)m3.x);
        unsigned r7 = *(const unsigned*)(basec + (unsigned)m3.z);
        EDGE2(m0.x, m0.y, r0); EDGE2(m0.z, m0.w, r1);
        EDGE2(m1.x, m1.y, r2); EDGE2(m1.z, m1.w, r3);
        EDGE2(m2.x, m2.y, r4); EDGE2(m2.z, m2.w, r5);
        EDGE2(m3.x, m3.y, r6); EDGE2(m3.z, m3.w, r7);
        c += 8;
    }
    for (; c < end; ++c) {
        int2 m = meta[c];
        unsigned rr = *(const unsigned*)(basec + (unsigned)m.x);
        EDGE2(m.x, m.y, rr);
    }
}

// ---------------- layer 0: tagsort + gather + GEMM (one group per block) ---
__global__ __launch_bounds__(512) void layer0_kernel(
        const unsigned short* __restrict__ cur,   // bf16 (= vb for L0)
        const unsigned short* __restrict__ vb,
        const int2*  __restrict__ metaT,          // group-CSR, tagged
        const int*   __restrict__ goff,
        int2* __restrict__ meta,                  // out: node-exact CSR
        int*  __restrict__ off,                   // out: node offsets
        const uint4* __restrict__ wfrag,
        const float* __restrict__ bias,
        unsigned short* __restrict__ out_bf) {
    __shared__ unsigned short xlds[64 * XPAD];    // 17408 B
    __shared__ int c64[64], b64[65], cu64[64];
    int tid = threadIdx.x;
    int wv  = tid >> 6, lane = tid & 63;
    int g   = blockIdx.x;
    int sbeg = goff[g], send = goff[g + 1];

    // ---- tagsort: 64-bin count + scan + scatter into node-exact meta ----
    if (tid < 64) c64[tid] = 0;
    __syncthreads();
    for (int i = sbeg + tid; i < send; i += 512)
        atomicAdd(&c64[(metaT[i].x >> 24) & 63], 1);
    __syncthreads();
    if (tid == 0) {
        int run = 0;
        #pragma unroll
        for (int t = 0; t < 64; ++t) { b64[t] = run; cu64[t] = run; run += c64[t]; }
        b64[64] = run;
    }
    __syncthreads();
    if (tid < 64) {
        int node = g * 64 + tid;
        if (node <= N_NODES) off[node] = sbeg + b64[tid];
    }
    for (int i = sbeg + tid; i < send; i += 512) {
        int2 m = metaT[i];
        int tag = (m.x >> 24) & 63;
        int lr = atomicAdd(&cu64[tag], 1);
        meta[sbeg + lr] = make_int2(m.x & 0x00FFFFFF, m.y);
    }
    __syncthreads();   // meta writes drained; b64 stable

    // ---- gather (offsets from LDS b64) ----
    int n0 = g * 64 + wv * 8;
    int myoff = 0;
    if (lane < 9) myoff = sbeg + b64[wv * 8 + lane];
    const char* basec = (const char*)cur + lane * 4;

    #pragma unroll 1
    for (int q = 0; q < 8; ++q) {
        int nl = wv * 8 + q;
        int n  = n0 + q;
        float a0 = 0.f, a1 = 0.f;
        if (n < N_NODES) {
            unsigned vv = *(const unsigned*)((const char*)vb + (size_t)n * (DIM * 2) + lane * 4);
            a0 = bf_lo(vv); a1 = bf_hi(vv);
            int beg = __builtin_amdgcn_readlane(myoff, q);
            int end = __builtin_amdgcn_readlane(myoff, q + 1);
            gather_node(meta, basec, beg, end, a0, a1);
        }
        *(unsigned*)(xlds + nl * XPAD + lane * 2) =
            (unsigned)f2bf(a0) | ((unsigned)f2bf(a1) << 16);
    }
    __syncthreads();

    // ---- GEMM: wave wv -> rows (wv>>1)*16..+15, col-half (wv&1) ----
    int quad = lane >> 4, l16 = lane & 15;
    int rb = wv >> 1, nh = wv & 1;
    f32x4 acc[4];
    #pragma unroll
    for (int j = 0; j < 4; ++j) acc[j] = (f32x4){0.f, 0.f, 0.f, 0.f};

    const unsigned short* xp = xlds + (rb * 16 + l16) * XPAD + quad * 8;
    #pragma unroll
    for (int kk = 0; kk < 4; ++kk) {
        bf16x8 af = *(const bf16x8*)(xp + kk * 32);
        #pragma unroll
        for (int j = 0; j < 4; ++j) {
            uint4 w = wfrag[(kk * 8 + nh * 4 + j) * 64 + lane];
            bf16x8 bfr = __builtin_bit_cast(bf16x8, w);
            acc[j] = __builtin_amdgcn_mfma_f32_16x16x32_bf16(af, bfr, acc[j], 0, 0, 0);
        }
    }

    int orow0 = g * 64 + rb * 16 + quad * 4;
    #pragma unroll
    for (int j = 0; j < 4; ++j) {
        int col = (nh * 4 + j) * 16 + l16;
        float b = bias[col];
        #pragma unroll
        for (int r = 0; r < 4; ++r) {
            int orow = orow0 + r;
            if (orow < N_NODES)
                out_bf[(size_t)orow * DIM + col] = f2bf(fmaxf(acc[j][r] + b, 0.f));
        }
    }
}

// ---------------- layers 1/2: 8-wave 64-node fused gather+GEMM (R1, 60.5us) -
__global__ __launch_bounds__(512, 6) void layer_kernel(
        const unsigned short* __restrict__ cur,
        const unsigned short* __restrict__ vb,
        const int2*  __restrict__ meta,
        const int*   __restrict__ off,
        const uint4* __restrict__ wfrag,
        const float* __restrict__ bias,
        unsigned short* __restrict__ out_bf,
        float* __restrict__ out_f,
        int last) {
    __shared__ unsigned short xlds[64 * XPAD];    // 17408 B
    int tid  = threadIdx.x;
    int wv   = tid >> 6, lane = tid & 63;
    int g    = blockIdx.x;
    int n0   = g * 64 + wv * 8;

    int offidx = n0 + ((lane < 9) ? lane : 8);
    if (offidx > N_NODES) offidx = N_NODES;
    int myoff = off[offidx];
    const char* basec = (const char*)cur + lane * 4;

    #pragma unroll 1
    for (int q = 0; q < 8; ++q) {
        int nl = wv * 8 + q;
        int n  = n0 + q;
        float a0 = 0.f, a1 = 0.f;
        if (n < N_NODES) {
            unsigned vv = *(const unsigned*)((const char*)vb + (size_t)n * (DIM * 2) + lane * 4);
            a0 = bf_lo(vv); a1 = bf_hi(vv);
            int beg = __builtin_amdgcn_readlane(myoff, q);
            int end = __builtin_amdgcn_readlane(myoff, q + 1);
            gather_node(meta, basec, beg, end, a0, a1);
        }
        *(unsigned*)(xlds + nl * XPAD + lane * 2) =
            (unsigned)f2bf(a0) | ((unsigned)f2bf(a1) << 16);
    }
    __syncthreads();

    // ---- GEMM: wave wv -> rows (wv>>1)*16..+15, col-half (wv&1) ----
    int quad = lane >> 4, l16 = lane & 15;
    int rb = wv >> 1, nh = wv & 1;
    f32x4 acc[4];
    #pragma unroll
    for (int j = 0; j < 4; ++j) acc[j] = (f32x4){0.f, 0.f, 0.f, 0.f};

    const unsigned short* xp = xlds + (rb * 16 + l16) * XPAD + quad * 8;
    #pragma unroll
    for (int kk = 0; kk < 4; ++kk) {
        bf16x8 af = *(const bf16x8*)(xp + kk * 32);
        #pragma unroll
        for (int j = 0; j < 4; ++j) {
            uint4 w = wfrag[(kk * 8 + nh * 4 + j) * 64 + lane];
            bf16x8 bfr = __builtin_bit_cast(bf16x8, w);
            acc[j] = __builtin_amdgcn_mfma_f32_16x16x32_bf16(af, bfr, acc[j], 0, 0, 0);
        }
    }

    int orow0 = g * 64 + rb * 16 + quad * 4;
    #pragma unroll
    for (int j = 0; j < 4; ++j) {
        int col = (nh * 4 + j) * 16 + l16;
        float b = bias[col];
        #pragma unroll
        for (int r = 0; r < 4; ++r) {
            int orow = orow0 + r;
            if (orow < N_NODES) {
                float val = fmaxf(acc[j][r] + b, 0.f);
                if (last) out_f[(size_t)orow * DIM + col] = val;
                else      out_bf[(size_t)orow * DIM + col] = f2bf(val);
            }
        }
    }
}

// ---------------------------------------------------------------------------
extern "C" void kernel_launch(void* const* d_in, const int* in_sizes, int n_in,
                              void* d_out, int out_size, void* d_ws, size_t ws_size,
                              hipStream_t stream) {
    const float* v     = (const float*)d_in[0];
    const float* e     = (const float*)d_in[1];
    const int*   src   = (const int*)  d_in[2];
    const int*   dst   = (const int*)  d_in[3];
    const float* Aw    = (const float*)d_in[4];
    const float* Ab    = (const float*)d_in[5];
    const float* rs    = (const float*)d_in[6];
    const float* sigma = (const float*)d_in[7];
    float* out = (float*)d_out;

    // ---- workspace layout (~51.5 MB) ----
    char* p = (char*)d_ws;
    int2*           meta  = (int2*)p;            p += (size_t)N_EDGES * 8;       // 12.8 MB (final CSR)
    unsigned short* bufV  = (unsigned short*)p;  p += (size_t)N_PAD * DIM * 2;   // 12.81 MB (pristine bf16 v)
    unsigned short* bufA  = (unsigned short*)p;  p += (size_t)N_PAD * DIM * 2;   // 12.81 MB (metaT / L1 out)
    unsigned short* bufB  = (unsigned short*)p;  p += (size_t)N_PAD * DIM * 2;   // 12.81 MB (partials / L0 out)
    uint4*          wfrag = (uint4*)p;           p += 2048 * 16;                 //  32 KB
    int*            off   = (int*)p;             p += (size_t)(N_NODES + 2) * 4;
    int*            goff  = (int*)p;             p += (NGROUP + 2) * 4;
    // aliases (dead before host buffer's first real write):
    int2* metaT    = (int2*)bufA;                // unsorted group-CSR, dead after layer0
    int*  partial  = (int*)bufB;                 // NB_PRE*NGROUP*4 = 1.6 MB
    int*  pbase    = partial + NB_PRE * NGROUP;  // 1.6 MB, dead after reorder
    int*  partial2 = pbase + NB_PRE * NGROUP;    // NB_SUB*NGROUP*4 = 25 KB

    preA_kernel<<<NB_CONV + NB_WPREP + NB_PRE, 256, 0, stream>>>(
        v, bufV, Aw, wfrag, dst, partial);
    ktot2_kernel<<<4 * NB_SUB, 256, 0, stream>>>(partial, partial2);
    kscan_kernel<<<1, 256, 0, stream>>>(partial2, goff);
    kbase2_kernel<<<4 * NB_SUB, 256, 0, stream>>>(partial, partial2, goff, pbase);
    reorder_kernel<<<NB_RE, 512, 0, stream>>>(e, src, dst, rs, sigma, pbase, metaT);

    // L0: tagsort + gather(bufV) + gemm -> bufB   (consumes metaT in bufA)
    layer0_kernel<<<NGROUP, 512, 0, stream>>>(
        bufV, bufV, metaT, goff, meta, off, wfrag, Ab, bufB);
    // L1: gather(bufB) + gemm -> bufA  (8-wave 64-node, measured 60.5us in R1)
    layer_kernel<<<NGROUP, 512, 0, stream>>>(
        bufB, bufV, meta, off, wfrag, Ab, bufA, nullptr, 0);
    // L2: gather(bufA) + gemm -> out (fp32)
    layer_kernel<<<NGROUP, 512, 0, stream>>>(
        bufA, bufV, meta, off, wfrag, Ab, nullptr, out, 1);
}

// Round 8
// 344.474 us; speedup vs baseline: 1.7108x; 1.0481x over previous
//
#include <hip/hip_runtime.h>
#include <math.h>

#define N_NODES 50000
#define N_PAD   50048              // rows padded to multiple of 64
#define N_EDGES 1600000
#define DIM     128
#define RCUT    5.0f
#define NGROUP  (N_PAD / 64)       // 782 groups of 64 nodes
#define NB_PRE  512
#define CH_PRE  (N_EDGES / NB_PRE) // 3125 edges per preA histogram chunk
#define NB_CONV 6250               // convert blocks in preA
#define NB_WPREP 8                 // wprep blocks in preA
#define NB_RE   128                // reorder blocks (4 preA chunks each)
#define CH_RE   (N_EDGES / NB_RE)  // 12500 edges per reorder block
#define XPAD    136                // LDS X tile row stride in bf16 (272 B)
#define NTILE   (N_PAD / 16)       // 3128 16-node tiles for layer12
#define BST     65                 // padded bin stride: bank=(wv+tag)&31

typedef __attribute__((ext_vector_type(8))) __bf16 bf16x8;
typedef __attribute__((ext_vector_type(4))) float  f32x4;

// ---------------- bf16 helpers ----------------
__device__ __forceinline__ float bf_lo(unsigned int u) { return __uint_as_float(u << 16); }
__device__ __forceinline__ float bf_hi(unsigned int u) { return __uint_as_float(u & 0xffff0000u); }
__device__ __forceinline__ unsigned short f2bf(float x) {
    unsigned int u = __float_as_uint(x);
    u += 0x7fffu + ((u >> 16) & 1u);   // round-to-nearest-even
    return (unsigned short)(u >> 16);
}

// ---------------- preA: convert v->bf16  |  W->frags  |  group-64 histogram ---
__global__ __launch_bounds__(256) void preA_kernel(
        const float* __restrict__ v, unsigned short* __restrict__ vb,
        const float* __restrict__ Aw, uint4* __restrict__ wfrag,
        const int* __restrict__ dst, int* __restrict__ partial) {
    int b = blockIdx.x;
    if (b < NB_CONV) {
        int i = b * 256 + threadIdx.x;           // exactly N_NODES*DIM/4
        float4 x = ((const float4*)v)[i];
        uint2 o;
        o.x = (unsigned)f2bf(x.x) | ((unsigned)f2bf(x.y) << 16);
        o.y = (unsigned)f2bf(x.z) | ((unsigned)f2bf(x.w) << 16);
        ((uint2*)vb)[i] = o;
    } else if (b < NB_CONV + NB_WPREP) {
        int t = (b - NB_CONV) * 256 + threadIdx.x;   // 0..2047
        int lane = t & 63, nt = (t >> 6) & 7, kk = t >> 9;
        int n  = nt * 16 + (lane & 15);
        int k0 = kk * 32 + (lane >> 4) * 8;
        unsigned short h[8];
        #pragma unroll
        for (int i = 0; i < 8; ++i) h[i] = f2bf(Aw[n * DIM + k0 + i]);
        uint4 o;
        o.x = h[0] | ((unsigned)h[1] << 16); o.y = h[2] | ((unsigned)h[3] << 16);
        o.z = h[4] | ((unsigned)h[5] << 16); o.w = h[6] | ((unsigned)h[7] << 16);
        wfrag[t] = o;
    } else {
        __shared__ int h[NGROUP];                // 3.1 KB
        int cb = b - NB_CONV - NB_WPREP, tid = threadIdx.x;
        for (int g = tid; g < NGROUP; g += 256) h[g] = 0;
        __syncthreads();
        int beg = cb * CH_PRE, end = beg + CH_PRE;
        for (int i = beg + tid; i < end; i += 256)
            atomicAdd(&h[dst[i] >> 6], 1);       // LDS atomic
        __syncthreads();
        for (int g = tid; g < NGROUP; g += 256) partial[cb * NGROUP + g] = h[g];
    }
}

// ---------------- 2-level partial sums: partial4[128][g], sum64[8][g] ------
// 32 blocks: (gb = blockIdx&3, qq = blockIdx>>2); each covers 64 preA chunks.
__global__ __launch_bounds__(256) void ktot2_kernel(const int* __restrict__ partial,
                                                    int* __restrict__ partial4,
                                                    int* __restrict__ sum64) {
    int gb = blockIdx.x & 3, qq = blockIdx.x >> 2;
    int g = gb * 256 + threadIdx.x;
    if (g >= NGROUP) return;
    int acc = 0;
    #pragma unroll 1
    for (int j = 0; j < 16; ++j) {
        int s4 = 0;
        #pragma unroll
        for (int c = 0; c < 4; ++c)
            s4 += partial[(qq * 64 + j * 4 + c) * NGROUP + g];
        partial4[(qq * 16 + j) * NGROUP + g] = s4;
        acc += s4;
    }
    sum64[qq * NGROUP + g] = acc;
}

// ---------------- exclusive scan over 782 group totals (from sum64) --------
__global__ __launch_bounds__(256) void kscan_kernel(const int* __restrict__ sum64,
                                                    int* __restrict__ goff) {
    __shared__ int part[256];
    int tid = threadIdx.x;
    int i0 = tid * 4;
    int v[4]; int s = 0;
    #pragma unroll
    for (int k = 0; k < 4; ++k) {
        int i = i0 + k; int t = 0;
        if (i < NGROUP) {
            #pragma unroll
            for (int qq = 0; qq < 8; ++qq) t += sum64[qq * NGROUP + i];
        }
        v[k] = t; s += t;
    }
    part[tid] = s; __syncthreads();
    for (int d = 1; d < 256; d <<= 1) {
        int val = (tid >= d) ? part[tid - d] : 0;
        __syncthreads(); part[tid] += val; __syncthreads();
    }
    int run = (tid == 0) ? 0 : part[tid - 1];
    #pragma unroll
    for (int k = 0; k < 4; ++k) {
        int i = i0 + k;
        if (i < NGROUP) { goff[i] = run; run += v[k]; }
    }
    if (tid == 0) goff[NGROUP] = N_EDGES;
}

// ---------------- reorder: self-computed base + group-CSR scatter ----------
// Block b covers preA chunks 4b..4b+3 (12500 edges). Its base per group:
// goff[g] + sum of sum64 for supers < b/16 + partial4 prefix within super.
__global__ __launch_bounds__(512) void reorder_kernel(
        const float* __restrict__ e,
        const int*   __restrict__ src,
        const int*   __restrict__ dst,
        const float* __restrict__ rs,
        const float* __restrict__ sigma,
        const int*   __restrict__ goff,
        const int*   __restrict__ partial4,
        const int*   __restrict__ sum64,
        int2* __restrict__ metaT) {
    __shared__ int base[NGROUP];
    __shared__ int cnt[NGROUP];
    int b = blockIdx.x, tid = threadIdx.x;
    int q = b >> 4;                              // super-chunk (16 blocks each)
    for (int g = tid; g < NGROUP; g += 512) {
        int run = goff[g];
        for (int qq = 0; qq < q; ++qq) run += sum64[qq * NGROUP + g];
        for (int j = q * 16; j < b; ++j) run += partial4[j * NGROUP + g];
        base[g] = run; cnt[g] = 0;
    }
    __syncthreads();
    float rsv = rs[0], sg = sigma[0];
    int beg = b * CH_RE, end = beg + CH_RE;
    for (int i = beg + tid; i < end; i += 512) {
        float r  = e[i];
        float d  = r - rsv;
        float gauss = expf(-(d * d) / (sg * sg));
        float cut   = 0.5f * cosf(r * (float)(M_PI / (double)RCUT));
        cut = (r < RCUT) ? cut : 0.0f;
        float fe = gauss * cut;
        int dn = dst[i];
        int g  = dn >> 6;
        int lr = atomicAdd(&cnt[g], 1);          // LDS atomic
        metaT[base[g] + lr] = make_int2(src[i] * (DIM * 2) | ((dn & 63) << 24),
                                        __float_as_int(fe));
    }
}

// ---------------- shared gather inner loop ----------------
#define EDGE2(mx, mf, rr)                                        \
    do {                                                         \
        float ff = __int_as_float(mf);                           \
        a0 = fmaf(ff, bf_lo(rr), a0);                            \
        a1 = fmaf(ff, bf_hi(rr), a1);                            \
    } while (0)

__device__ __forceinline__ void gather_node(
        const int2* __restrict__ meta, const char* basec,
        int beg, int end, float& a0, float& a1) {
    int c = beg;
    if ((c & 1) && c < end) {
        int2 m = meta[c];
        unsigned rr = *(const unsigned*)(basec + (unsigned)m.x);
        EDGE2(m.x, m.y, rr);
        ++c;
    }
    for (; c + 16 <= end; c += 16) {
        int4 m0 = *(const int4*)(meta + c);
        int4 m1 = *(const int4*)(meta + c + 2);
        int4 m2 = *(const int4*)(meta + c + 4);
        int4 m3 = *(const int4*)(meta + c + 6);
        int4 m4 = *(const int4*)(meta + c + 8);
        int4 m5 = *(const int4*)(meta + c + 10);
        int4 m6 = *(const int4*)(meta + c + 12);
        int4 m7 = *(const int4*)(meta + c + 14);
        unsigned r0  = *(const unsigned*)(basec + (unsigned)m0.x);
        unsigned r1  = *(const unsigned*)(basec + (unsigned)m0.z);
        unsigned r2  = *(const unsigned*)(basec + (unsigned)m1.x);
        unsigned r3  = *(const unsigned*)(basec + (unsigned)m1.z);
        unsigned r4  = *(const unsigned*)(basec + (unsigned)m2.x);
        unsigned r5  = *(const unsigned*)(basec + (unsigned)m2.z);
        unsigned r6  = *(const unsigned*)(basec + (unsigned)m3.x);
        unsigned r7  = *(const unsigned*)(basec + (unsigned)m3.z);
        unsigned r8  = *(const unsigned*)(basec + (unsigned)m4.x);
        unsigned r9  = *(const unsigned*)(basec + (unsigned)m4.z);
        unsigned r10 = *(const unsigned*)(basec + (unsigned)m5.x);
        unsigned r11 = *(const unsigned*)(basec + (unsigned)m5.z);
        unsigned r12 = *(const unsigned*)(basec + (unsigned)m6.x);
        unsigned r13 = *(const unsigned*)(basec + (unsigned)m6.z);
        unsigned r14 = *(const unsigned*)(basec + (unsigned)m7.x);
        unsigned r15 = *(const unsigned*)(basec + (unsigned)m7.z);
        EDGE2(m0.x, m0.y, r0);  EDGE2(m0.z, m0.w, r1);
        EDGE2(m1.x, m1.y, r2);  EDGE2(m1.z, m1.w, r3);
        EDGE2(m2.x, m2.y, r4);  EDGE2(m2.z, m2.w, r5);
        EDGE2(m3.x, m3.y, r6);  EDGE2(m3.z, m3.w, r7);
        EDGE2(m4.x, m4.y, r8);  EDGE2(m4.z, m4.w, r9);
        EDGE2(m5.x, m5.y, r10); EDGE2(m5.z, m5.w, r11);
        EDGE2(m6.x, m6.y, r12); EDGE2(m6.z, m6.w, r13);
        EDGE2(m7.x, m7.y, r14); EDGE2(m7.z, m7.w, r15);
    }
    if (c + 8 <= end) {
        int4 m0 = *(const int4*)(meta + c);
        int4 m1 = *(const int4*)(meta + c + 2);
        int4 m2 = *(const int4*)(meta + c + 4);
        int4 m3 = *(const int4*)(meta + c + 6);
        unsigned r0 = *(const unsigned*)(basec + (unsigned)m0.x);
        unsigned r1 = *(const unsigned*)(basec + (unsigned)m0.z);
        unsigned r2 = *(const unsigned*)(basec + (unsigned)m1.x);
        unsigned r3 = *(const unsigned*)(basec + (unsigned)m1.z);
        unsigned r4 = *(const unsigned*)(basec + (unsigned)m2.x);
        unsigned r5 = *(const unsigned*)(basec + (unsigned)m2.z);
        unsigned r6 = *(const unsigned*)(basec + (unsigned)m3.x);
        unsigned r7 = *(const unsigned*)(basec + (unsigned)m3.z);
        EDGE2(m0.x, m0.y, r0); EDGE2(m0.z, m0.w, r1);
        EDGE2(m1.x, m1.y, r2); EDGE2(m1.z, m1.w, r3);
        EDGE2(m2.x, m2.y, r4); EDGE2(m2.z, m2.w, r5);
        EDGE2(m3.x, m3.y, r6); EDGE2(m3.z, m3.w, r7);
        c += 8;
    }
    for (; c < end; ++c) {
        int2 m = meta[c];
        unsigned rr = *(const unsigned*)(basec + (unsigned)m.x);
        EDGE2(m.x, m.y, rr);
    }
}

// ---------------- layer 0: padded per-wave tagsort + gather + GEMM ---------
__global__ __launch_bounds__(512) void layer0_kernel(
        const unsigned short* __restrict__ cur,   // bf16 (= vb for L0)
        const unsigned short* __restrict__ vb,
        const int2*  __restrict__ metaT,          // group-CSR, tagged
        const int*   __restrict__ goff,
        int2* __restrict__ meta,                  // out: node-exact CSR
        int*  __restrict__ off,                   // out: node offsets
        const uint4* __restrict__ wfrag,
        const float* __restrict__ bias,
        unsigned short* __restrict__ out_bf) {
    __shared__ unsigned short xlds[64 * XPAD];    // 17408 B
    __shared__ int cntW[8 * BST];                 // per-wave bins, bank-rotated
    __shared__ int curW[8 * BST];                 // per-wave cursors
    __shared__ int b64[65];
    int tid = threadIdx.x;
    int wv  = tid >> 6, lane = tid & 63;
    int g   = blockIdx.x;
    int sbeg = goff[g], send = goff[g + 1];

    // ---- per-wave 64-bin count (bank-distinct: addr = wv*65+tag) ----
    for (int i = tid; i < 8 * BST; i += 512) cntW[i] = 0;
    __syncthreads();
    for (int i = sbeg + tid; i < send; i += 512)
        atomicAdd(&cntW[wv * BST + ((metaT[i].x >> 24) & 63)], 1);
    __syncthreads();
    // ---- wave-parallel scan over tags + per-wave cursor bases ----
    if (tid < 64) {
        int x = 0;
        #pragma unroll
        for (int w = 0; w < 8; ++w) x += cntW[w * BST + tid];
        int incl = x;
        #pragma unroll
        for (int d = 1; d < 64; d <<= 1) {
            int y = __shfl_up(incl, d, 64);
            if (tid >= d) incl += y;
        }
        int excl = incl - x;
        b64[tid] = excl;
        if (tid == 63) b64[64] = incl;
        int run = excl;
        #pragma unroll
        for (int w = 0; w < 8; ++w) { curW[w * BST + tid] = run; run += cntW[w * BST + tid]; }
        int node = g * 64 + tid;
        if (node <= N_NODES) off[node] = sbeg + excl;
    }
    __syncthreads();
    // ---- scatter into node-exact meta (per-wave bank-distinct cursors) ----
    for (int i = sbeg + tid; i < send; i += 512) {
        int2 m = metaT[i];
        int lr = atomicAdd(&curW[wv * BST + ((m.x >> 24) & 63)], 1);
        meta[sbeg + lr] = make_int2(m.x & 0x00FFFFFF, m.y);
    }
    __syncthreads();   // meta writes issued; b64 stable

    // ---- gather (offsets from LDS b64) ----
    int n0 = g * 64 + wv * 8;
    int myoff = 0;
    if (lane < 9) myoff = sbeg + b64[wv * 8 + lane];
    const char* basec = (const char*)cur + lane * 4;

    #pragma unroll 1
    for (int q = 0; q < 8; ++q) {
        int nl = wv * 8 + q;
        int n  = n0 + q;
        float a0 = 0.f, a1 = 0.f;
        if (n < N_NODES) {
            unsigned vv = *(const unsigned*)((const char*)vb + (size_t)n * (DIM * 2) + lane * 4);
            a0 = bf_lo(vv); a1 = bf_hi(vv);
            int beg = __builtin_amdgcn_readlane(myoff, q);
            int end = __builtin_amdgcn_readlane(myoff, q + 1);
            gather_node(meta, basec, beg, end, a0, a1);
        }
        *(unsigned*)(xlds + nl * XPAD + lane * 2) =
            (unsigned)f2bf(a0) | ((unsigned)f2bf(a1) << 16);
    }
    __syncthreads();

    // ---- GEMM: wave wv -> rows (wv>>1)*16..+15, col-half (wv&1) ----
    int quad = lane >> 4, l16 = lane & 15;
    int rb = wv >> 1, nh = wv & 1;
    f32x4 acc[4];
    #pragma unroll
    for (int j = 0; j < 4; ++j) acc[j] = (f32x4){0.f, 0.f, 0.f, 0.f};

    const unsigned short* xp = xlds + (rb * 16 + l16) * XPAD + quad * 8;
    #pragma unroll
    for (int kk = 0; kk < 4; ++kk) {
        bf16x8 af = *(const bf16x8*)(xp + kk * 32);
        #pragma unroll
        for (int j = 0; j < 4; ++j) {
            uint4 w = wfrag[(kk * 8 + nh * 4 + j) * 64 + lane];
            bf16x8 bfr = __builtin_bit_cast(bf16x8, w);
            acc[j] = __builtin_amdgcn_mfma_f32_16x16x32_bf16(af, bfr, acc[j], 0, 0, 0);
        }
    }

    int orow0 = g * 64 + rb * 16 + quad * 4;
    #pragma unroll
    for (int j = 0; j < 4; ++j) {
        int col = (nh * 4 + j) * 16 + l16;
        float b = bias[col];
        #pragma unroll
        for (int r = 0; r < 4; ++r) {
            int orow = orow0 + r;
            if (orow < N_NODES)
                out_bf[(size_t)orow * DIM + col] = f2bf(fmaxf(acc[j][r] + b, 0.f));
        }
    }
}

// ---------------- layers 1/2: 2-wave 16-node fused gather+GEMM (R4, fast) --
__global__ __launch_bounds__(128, 8) void layer12_kernel(
        const unsigned short* __restrict__ cur,
        const unsigned short* __restrict__ vb,
        const int2*  __restrict__ meta,
        const int*   __restrict__ off,
        const uint4* __restrict__ wfrag,
        const float* __restrict__ bias,
        unsigned short* __restrict__ out_bf,
        float* __restrict__ out_f,
        int last) {
    __shared__ unsigned short xlds[16 * XPAD];    // 4352 B
    int tid = threadIdx.x;
    int wv  = tid >> 6, lane = tid & 63;          // wv in {0,1}
    int tile = blockIdx.x;
    int n0  = tile * 16 + wv * 8;

    int offidx = n0 + ((lane < 9) ? lane : 8);
    if (offidx > N_NODES) offidx = N_NODES;
    int myoff = off[offidx];
    const char* basec = (const char*)cur + lane * 4;

    #pragma unroll 1
    for (int q = 0; q < 8; ++q) {
        int nl = wv * 8 + q;
        int n  = n0 + q;
        float a0 = 0.f, a1 = 0.f;
        if (n < N_NODES) {
            unsigned vv = *(const unsigned*)((const char*)vb + (size_t)n * (DIM * 2) + lane * 4);
            a0 = bf_lo(vv); a1 = bf_hi(vv);
            int beg = __builtin_amdgcn_readlane(myoff, q);
            int end = __builtin_amdgcn_readlane(myoff, q + 1);
            gather_node(meta, basec, beg, end, a0, a1);
        }
        *(unsigned*)(xlds + nl * XPAD + lane * 2) =
            (unsigned)f2bf(a0) | ((unsigned)f2bf(a1) << 16);
    }
    __syncthreads();

    // ---- GEMM: both waves cover all 16 rows; wave = col-half ----
    int quad = lane >> 4, l16 = lane & 15;
    f32x4 acc[4];
    #pragma unroll
    for (int j = 0; j < 4; ++j) acc[j] = (f32x4){0.f, 0.f, 0.f, 0.f};

    const unsigned short* xp = xlds + l16 * XPAD + quad * 8;
    #pragma unroll
    for (int kk = 0; kk < 4; ++kk) {
        bf16x8 af = *(const bf16x8*)(xp + kk * 32);
        #pragma unroll
        for (int j = 0; j < 4; ++j) {
            uint4 w = wfrag[(kk * 8 + wv * 4 + j) * 64 + lane];
            bf16x8 bfr = __builtin_bit_cast(bf16x8, w);
            acc[j] = __builtin_amdgcn_mfma_f32_16x16x32_bf16(af, bfr, acc[j], 0, 0, 0);
        }
    }

    int orow0 = tile * 16 + quad * 4;
    #pragma unroll
    for (int j = 0; j < 4; ++j) {
        int col = (wv * 4 + j) * 16 + l16;
        float b = bias[col];
        #pragma unroll
        for (int r = 0; r < 4; ++r) {
            int orow = orow0 + r;
            if (orow < N_NODES) {
                float val = fmaxf(acc[j][r] + b, 0.f);
                if (last) out_f[(size_t)orow * DIM + col] = val;
                else      out_bf[(size_t)orow * DIM + col] = f2bf(val);
            }
        }
    }
}

// ---------------------------------------------------------------------------
extern "C" void kernel_launch(void* const* d_in, const int* in_sizes, int n_in,
                              void* d_out, int out_size, void* d_ws, size_t ws_size,
                              hipStream_t stream) {
    const float* v     = (const float*)d_in[0];
    const float* e     = (const float*)d_in[1];
    const int*   src   = (const int*)  d_in[2];
    const int*   dst   = (const int*)  d_in[3];
    const float* Aw    = (const float*)d_in[4];
    const float* Ab    = (const float*)d_in[5];
    const float* rs    = (const float*)d_in[6];
    const float* sigma = (const float*)d_in[7];
    float* out = (float*)d_out;

    // ---- workspace layout (~51.5 MB) ----
    char* p = (char*)d_ws;
    int2*           meta  = (int2*)p;            p += (size_t)N_EDGES * 8;       // 12.8 MB (final CSR)
    unsigned short* bufV  = (unsigned short*)p;  p += (size_t)N_PAD * DIM * 2;   // 12.81 MB (pristine bf16 v)
    unsigned short* bufA  = (unsigned short*)p;  p += (size_t)N_PAD * DIM * 2;   // 12.81 MB (metaT / L1 out)
    unsigned short* bufB  = (unsigned short*)p;  p += (size_t)N_PAD * DIM * 2;   // 12.81 MB (partials / L0 out)
    uint4*          wfrag = (uint4*)p;           p += 2048 * 16;                 //  32 KB
    int*            off   = (int*)p;             p += (size_t)(N_NODES + 2) * 4;
    int*            goff  = (int*)p;             p += (NGROUP + 2) * 4;
    // aliases (dead before host buffer's first real write):
    int2* metaT    = (int2*)bufA;                // unsorted group-CSR, dead after layer0
    int*  partial  = (int*)bufB;                 // [512][NGROUP] = 1.6 MB
    int*  partial4 = partial + NB_PRE * NGROUP;  // [128][NGROUP] = 400 KB
    int*  sum64    = partial4 + 128 * NGROUP;    // [8][NGROUP]   =  25 KB

    preA_kernel<<<NB_CONV + NB_WPREP + NB_PRE, 256, 0, stream>>>(
        v, bufV, Aw, wfrag, dst, partial);
    ktot2_kernel<<<32, 256, 0, stream>>>(partial, partial4, sum64);
    kscan_kernel<<<1, 256, 0, stream>>>(sum64, goff);
    reorder_kernel<<<NB_RE, 512, 0, stream>>>(
        e, src, dst, rs, sigma, goff, partial4, sum64, metaT);

    // L0: tagsort + gather(bufV) + gemm -> bufB   (consumes metaT in bufA)
    layer0_kernel<<<NGROUP, 512, 0, stream>>>(
        bufV, bufV, metaT, goff, meta, off, wfrag, Ab, bufB);
    // L1: gather(bufB) + gemm -> bufA
    layer12_kernel<<<NTILE, 128, 0, stream>>>(
        bufB, bufV, meta, off, wfrag, Ab, bufA, nullptr, 0);
    // L2: gather(bufA) + gemm -> out (fp32)
    layer12_kernel<<<NTILE, 128, 0, stream>>>(
        bufA, bufV, meta, off, wfrag, Ab, nullptr, out, 1);
}